// Round 10
// baseline (145.192 us; speedup 1.0000x reference)
//
#include <hip/hip_runtime.h>

// YOLO loss, S=14, B=2, C=20, N_EL=30, batch=4096, 16 boxes/row.
// R9 decomposition + sparse stream fetch:
//   stream part (392 blocks x 256 thr x 8 cells, EXACT cover): every cell
//     contributes 0.5*(p4^2+p9^2). Only ch4/ch9 are LOADED (2 dwords per
//     120B row -> ~80B/cell in 64B sectors vs 120B dense, ~33% fewer bytes).
//   obj part (first 256 blocks, 16 whole rows each, exact no-overlap):
//     LDS winner map (atomicMax (k<<8)|hot == last-wins scatter), winning
//     box of each obj cell adds class sum((v-t)^2, ch10..29) + contain +
//     5*loc - 0.5*(p4^2+p9^2)  (cancels the stream's spurious noobj term).
//   per-wave partial stores (no same-address atomics: +10us measured R5/R7);
//   1024-thread 1-block reduce -> out[0].

#define SGRID 14
#define CELLS 196
#define NEL 30
#define NBOX 16
#define PRED_PER_BATCH 5880
#define STREAM_TPB 256
#define CPT 8                                   // cells per thread (stream)
#define SCELLS (CPT * STREAM_TPB)               // 2048 cells per block
#define ROWS_PER_OBJ_BLOCK 16
#define OBJ_TILE (ROWS_PER_OBJ_BLOCK * CELLS)   // 3136 ints = 12.25 KB

__global__ __launch_bounds__(256) void yolo_fused_kernel(
    const float*  __restrict__ pred,
    const float4* __restrict__ boxes,
    const int*    __restrict__ classes,
    float* __restrict__ partials,      // 4 per block (per-wave)
    int ncells, int nrows, int objblocks)
{
    __shared__ int s_win[OBJ_TILE];

    const int tid = threadIdx.x;
    const int bid = blockIdx.x;
    const float cellw = (float)(1.0 / 14.0);   // match jnp: divide by float32(1/14)
    const bool isobj = bid < objblocks;

    // ---- obj prologue loads issued first (overlap with stream loads) ----
    float4 bx; int cls = 0;
    const int row = bid * ROWS_PER_OBJ_BLOCK + (tid >> 4);
    const int k   = tid & 15;
    const bool has_box = isobj && row < nrows;
    if (has_box) {
        bx  = boxes[row * NBOX + k];
        cls = classes[row * NBOX + k];
    }

    // ---- stream loads: ONLY ch4 and ch9 of each cell, batched in regs ----
    const int cbase = bid * SCELLS + tid;
    float v4a[CPT], v9a[CPT];
    if (bid * SCELLS + SCELLS <= ncells) {
        #pragma unroll
        for (int i = 0; i < CPT; ++i) {
            const float* r = pred + (size_t)(cbase + i * STREAM_TPB) * NEL;
            v4a[i] = r[4];  v9a[i] = r[9];
        }
    } else {
        #pragma unroll
        for (int i = 0; i < CPT; ++i) {
            int c = cbase + i * STREAM_TPB;
            if (c < ncells) {
                const float* r = pred + (size_t)c * NEL;
                v4a[i] = r[4];  v9a[i] = r[9];
            } else { v4a[i] = 0.0f; v9a[i] = 0.0f; }
        }
    }

    float loss = 0.0f;

    // ---- obj part: only the first 256 blocks ----
    if (isobj) {
        #pragma unroll
        for (int i = 0; i < (OBJ_TILE + STREAM_TPB - 1) / STREAM_TPB; ++i) {
            int idx = tid + i * STREAM_TPB;
            if (idx < OBJ_TILE) s_win[idx] = -1;
        }
        __syncthreads();
        float dx, dy, bw, bh; int cell = 0;
        if (has_box) {
            bw = bx.z - bx.x;  bh = bx.w - bx.y;
            float cx = (bx.x + bx.z) * 0.5f, cy = (bx.y + bx.w) * 0.5f;
            float fx = cx / cellw, fy = cy / cellw;
            float fi = fminf(fmaxf(ceilf(fx) - 1.0f, 0.0f), 13.0f);
            float fj = fminf(fmaxf(ceilf(fy) - 1.0f, 0.0f), 13.0f);
            dx = fx - fi;  dy = fy - fj;
            cell = (int)fj * SGRID + (int)fi;
            atomicMax(&s_win[(tid >> 4) * CELLS + cell], (k << 8) | (9 + cls));
        }
        __syncthreads();
        if (has_box) {
            int wv = s_win[(tid >> 4) * CELLS + cell];
            if ((wv >> 8) == k) {                  // this box won its cell
                const float* p = pred + (size_t)(row * CELLS + cell) * NEL;
                int hot = wv & 0xFF;               // 9..28 (cls 0 -> ch9, faithful)
                float a[10];
                #pragma unroll
                for (int j = 0; j < 5; ++j) {      // 8B-aligned float2 loads (LLC-hot)
                    float2 t = *(const float2*)(p + 2 * j);
                    a[2 * j] = t.x;  a[2 * j + 1] = t.y;
                }
                // class loss ch10..29 directly (hot==9 -> all targets 0)
                float csum = 0.0f;
                #pragma unroll
                for (int j = 0; j < 10; ++j) {
                    float2 t = *(const float2*)(p + 10 + 2 * j);
                    float d0 = t.x - ((10 + 2 * j) == hot ? 1.0f : 0.0f);
                    float d1 = t.y - ((11 + 2 * j) == hot ? 1.0f : 0.0f);
                    csum += d0 * d0 + d1 * d1;
                }
                loss += csum;
                // cancel the stream's spurious noobj term for this obj cell
                loss -= 0.5f * (a[4] * a[4] + a[9] * a[9]);
                // corner-format "IoU" of (dx,dy,w,h) rows verbatim (per reference)
                float area_t = (bw - dx) * (bh - dy);
                float iou[2];
                #pragma unroll
                for (int i = 0; i < 2; ++i) {
                    const float* q = a + i * 5;
                    float ltx = fmaxf(q[0], dx), lty = fmaxf(q[1], dy);
                    float rbx = fminf(q[2], bw), rby = fminf(q[3], bh);
                    float wi = fmaxf(rbx - ltx, 0.0f);
                    float hi = fmaxf(rby - lty, 0.0f);
                    float inter  = wi * hi;
                    float area_a = (q[2] - q[0]) * (q[3] - q[1]);
                    float uni    = area_a + area_t - inter;
                    iou[i] = inter / ((uni == 0.0f) ? 1.0f : uni);
                }
                int r = (iou[1] > iou[0]) ? 1 : 0; // argmax tie -> 0
                const float* q = a + r * 5;
                float dc = q[4] - 1.0f;            // contain
                loss += dc * dc;
                float lx = q[0] - dx, ly = q[1] - dy;  // 5 * loc
                float lw = sqrtf(q[2]) - sqrtf(bw);
                float lh = sqrtf(q[3]) - sqrtf(bh);
                loss += 5.0f * (lx * lx + ly * ly + lw * lw + lh * lh);
            }
        }
    }

    // ---- stream consume: pure 0.5*v^2 on conf channels ----
    #pragma unroll
    for (int i = 0; i < CPT; ++i) {
        loss = fmaf(0.5f * v4a[i], v4a[i], loss);
        loss = fmaf(0.5f * v9a[i], v9a[i], loss);
    }

    // ---- per-wave reduce -> plain store, no block barrier, no atomics ----
    #pragma unroll
    for (int off = 32; off > 0; off >>= 1)
        loss += __shfl_down(loss, off, 64);
    if ((tid & 63) == 0)
        partials[bid * 4 + (tid >> 6)] = loss;
}

__global__ __launch_bounds__(1024) void final_reduce_kernel(
    const float* __restrict__ partials, float* __restrict__ out, int n)
{
    float s = 0.0f;
    #pragma unroll 2
    for (int i = threadIdx.x; i < n; i += 1024) s += partials[i];
    #pragma unroll
    for (int off = 32; off > 0; off >>= 1)
        s += __shfl_down(s, off, 64);
    __shared__ float w16[16];
    if ((threadIdx.x & 63) == 0) w16[threadIdx.x >> 6] = s;
    __syncthreads();
    if (threadIdx.x < 64) {
        float t = (threadIdx.x < 16) ? w16[threadIdx.x] : 0.0f;
        #pragma unroll
        for (int off = 8; off > 0; off >>= 1)
            t += __shfl_down(t, off, 64);
        if (threadIdx.x == 0) out[0] = t;
    }
}

extern "C" void kernel_launch(void* const* d_in, const int* in_sizes, int n_in,
                              void* d_out, int out_size, void* d_ws, size_t ws_size,
                              hipStream_t stream) {
    const float* pred    = (const float*)d_in[0];
    const float* boxes   = (const float*)d_in[1];
    const int*   classes = (const int*)d_in[2];
    float* out = (float*)d_out;

    const int nrows  = in_sizes[0] / PRED_PER_BATCH;       // 4096
    const int ncells = nrows * CELLS;                      // 802816
    int sblocks = (ncells + SCELLS - 1) / SCELLS;          // 392 (exact)
    const int objblocks = (nrows + ROWS_PER_OBJ_BLOCK - 1) / ROWS_PER_OBJ_BLOCK;  // 256
    if (sblocks < objblocks) sblocks = objblocks;

    float* partials = (float*)d_ws;

    yolo_fused_kernel<<<dim3(sblocks), dim3(STREAM_TPB), 0, stream>>>(
        pred, (const float4*)boxes, classes, partials, ncells, nrows, objblocks);
    final_reduce_kernel<<<dim3(1), dim3(1024), 0, stream>>>(partials, out, sblocks * 4);
}